// Round 4
// baseline (94.199 us; speedup 1.0000x reference)
//
#include <hip/hip_runtime.h>
#include <cstdint>

typedef __bf16 bf16x8 __attribute__((ext_vector_type(8)));
typedef float floatx4 __attribute__((ext_vector_type(4)));

// M = 4096 rows, C(K) = 256. Two-kernel path:
//   K0 transpose_stage: fp32 (B,N,C,H,W) -> staged bf16 (16.8 MB total)
//   K1 gemm_softmax_partial: 256x256 tiles, XCD-swizzled so each XCD's 32
//      blocks share a 4bR x 8bC chunk -> 1.5 MB panel working set, L2-resident
//      (round-3 lesson: without this, inputs are re-served 16x from LLC/HBM at
//      ~4 TB/s = the whole 45 us). Counted-vmcnt pipeline (no vmcnt(0) drain
//      in the K-loop; slab s+1's 8 global_load_lds stay in flight across the
//      barrier and under COMPUTE(s)).
//
// Staged layout: Xs[rb(32)][s(4)][kk(2)][rowhi(8)][quad(4)][rowlo(16)][8 bf16]
// holding X[row = rb*128+rowhi*16+rowlo][k = s*64+kk*32+quad*8+j]; lane-linear
// for global_load_lds AND conflict-free (2-way) for ds_read_b128 fragments.

#define OFF_X     (0u)
#define OFF_Y     (2u*1024*1024)
#define OFF_PMAX  (4u*1024*1024)
#define OFF_PSUM  (5u*1024*1024)
#define OFF_DIAG  (6u*1024*1024)
#define OFF_LPART (OFF_DIAG + 16384u)
#define OFF_CPART (OFF_LPART + 256u)
#define OFF_CNT   (OFF_CPART + 256u)   // cnt[0]: combine arrival counter

#define AS1C(p) ((const __attribute__((address_space(1))) void*)(const void*)(p))
#define AS3(p)  ((__attribute__((address_space(3))) void*)(void*)(p))

// ---------------------------------------------------------------------------
// K0: fp32 -> staged bf16. One block per (b,n) slab (16 rows x 256 c = 16 KB
// contiguous). Block 0 zeroes the combine counter (kernel-boundary release
// makes it visible downstream).
// ---------------------------------------------------------------------------
__global__ __launch_bounds__(256) void transpose_stage(
    const float* __restrict__ pred, const float* __restrict__ gt,
    unsigned short* __restrict__ Xs, unsigned short* __restrict__ Ys,
    int* __restrict__ cnt) {
  int blk = blockIdx.x;
  const int t = threadIdx.x;
  if (blk == 0 && t < 33) cnt[t] = 0;
  const float* src;
  unsigned short* dst;
  int slab;
  if (blk < 256) { src = pred; dst = Xs; slab = blk; }
  else           { src = gt;   dst = Ys; slab = blk - 256; }
  const float* sb = src + slab * 4096;
  const int rb = slab >> 3, rowhi = slab & 7;
  #pragma unroll
  for (int half = 0; half < 2; ++half) {
    int c_ = half * 256 + t;                 // chunk id within slab, 0..511
    int rowlo = c_ & 15;
    int quad  = (c_ >> 4) & 3;
    int kk    = (c_ >> 6) & 1;
    int s     = c_ >> 7;
    int k0 = s * 64 + kk * 32 + quad * 8;
    unsigned int packed[4];
    #pragma unroll
    for (int jj = 0; jj < 4; ++jj) {
      unsigned int lohi[2];
      #pragma unroll
      for (int e = 0; e < 2; ++e) {
        float f = sb[(k0 + jj * 2 + e) * 16 + rowlo];
        unsigned int u = __float_as_uint(f);
        lohi[e] = (u + 0x7FFFu + ((u >> 16) & 1u)) >> 16;   // RNE -> bf16
      }
      packed[jj] = lohi[0] | (lohi[1] << 16);
    }
    unsigned short* o = dst + rb * 32768 +
        (unsigned)(s * 1024 + kk * 512 + rowhi * 64 + quad * 16 + rowlo) * 8;
    uint4 v; v.x = packed[0]; v.y = packed[1]; v.z = packed[2]; v.w = packed[3];
    *reinterpret_cast<uint4*>(o) = v;
  }
}

// ---------------------------------------------------------------------------
// K1: lossmat tile (256x256) = X @ Y^T, mfma_f32_16x16x32_bf16.
// 512 threads, 8 waves as 2x4 (rg,cg); wave tile 128x64 = 8x4 fragments.
// Grid: 256 linear blocks; h%8 selects XCD (observed round-robin), each XCD
// owns a 4bR x 8bC chunk. K in 4 slabs of 64 via dbuf 128 KB LDS; counted
// vmcnt(8) + raw s_barrier (asm memory clobbers fence the compiler; s_barrier
// has MIR side effects, so LDS ops can't cross at either level).
// ---------------------------------------------------------------------------
__global__ __launch_bounds__(512) void gemm_softmax_partial(
    const unsigned short* __restrict__ Xs, const unsigned short* __restrict__ Ys,
    float* __restrict__ pmax, float* __restrict__ psum, float* __restrict__ diag) {
  __shared__ __align__(16) unsigned short As[2][16384];  // 2 x 32 KB
  __shared__ __align__(16) unsigned short Bs[2][16384];  // 2 x 32 KB
  const int t = threadIdx.x;
  const int wave = t >> 6, lane = t & 63;
  const int rg = wave >> 2, cg = wave & 3;
  // XCD-aware swizzle: xcd = h&7 (round-robin dispatch), 32 slots per XCD as
  // 4 bR x 8 bC. Per-XCD panels: 4*128KB + 8*128KB = 1.5 MB -> L2-resident.
  const int h = blockIdx.x;
  const int xcd = h & 7, slot = h >> 3;
  const int bR = ((xcd >> 1) << 2) | (slot & 3);
  const int bC = ((xcd & 1) << 3) | (slot >> 2);
  const unsigned short* Ag = Xs + bR * 65536;   // rb groups 2bR, 2bR+1
  const unsigned short* Bg = Ys + bC * 65536;

  floatx4 acc[8][4];
  const floatx4 zero = {0.f, 0.f, 0.f, 0.f};
  #pragma unroll
  for (int i = 0; i < 8; ++i)
    #pragma unroll
    for (int j = 0; j < 4; ++j) acc[i][j] = zero;

  // Stage slab S into buffer BUF: 8 x global_load_lds(16B) per thread.
#define STAGE(BUF, S) do {                                                   \
    _Pragma("unroll") for (int it = 0; it < 4; ++it) {                       \
      int chunk = it * 512 + t;              /* 0..2047 */                   \
      int half = chunk >> 10, w_ = chunk & 1023;                             \
      __builtin_amdgcn_global_load_lds(                                      \
          AS1C(Ag + half * 32768 + (S) * 8192 + w_ * 8),                     \
          AS3(&As[BUF][(unsigned)chunk * 8]), 16, 0, 0);                     \
      __builtin_amdgcn_global_load_lds(                                      \
          AS1C(Bg + half * 32768 + (S) * 8192 + w_ * 8),                     \
          AS3(&Bs[BUF][(unsigned)chunk * 8]), 16, 0, 0);                     \
    }                                                                        \
  } while (0)

#define COMPUTE(BUF) do {                                                    \
    _Pragma("unroll") for (int kk = 0; kk < 2; ++kk) {                       \
      bf16x8 b[4];                                                           \
      _Pragma("unroll") for (int fc = 0; fc < 4; ++fc) {                     \
        int gc = cg * 4 + fc;                                                \
        b[fc] = *reinterpret_cast<const bf16x8*>(                            \
            &Bs[BUF][(unsigned)((gc >> 3) * 8192 + kk * 4096 +               \
                                (gc & 7) * 512 + lane * 8)]);                \
      }                                                                      \
      _Pragma("unroll") for (int fr = 0; fr < 8; ++fr) {                     \
        bf16x8 a = *reinterpret_cast<const bf16x8*>(                         \
            &As[BUF][(unsigned)(rg * 8192 + kk * 4096 + fr * 512 +           \
                                lane * 8)]);                                 \
        _Pragma("unroll") for (int fc = 0; fc < 4; ++fc)                     \
          acc[fr][fc] = __builtin_amdgcn_mfma_f32_16x16x32_bf16(             \
              a, b[fc], acc[fr][fc], 0, 0, 0);                               \
      }                                                                      \
    }                                                                        \
  } while (0)

// Acquire: drain own oldest loads to vmcnt(N), then barrier (all waves'
// portions resident), compiler-fenced on both sides.
#define BAR_ACQ(N) do {                                                      \
    asm volatile("s_waitcnt vmcnt(" #N ")" ::: "memory");                    \
    __builtin_amdgcn_s_barrier();                                            \
    asm volatile("" ::: "memory");                                           \
  } while (0)
// Release: all waves done reading a buffer before it can be overwritten.
#define BAR_REL() do {                                                       \
    asm volatile("" ::: "memory");                                           \
    __builtin_amdgcn_s_barrier();                                            \
  } while (0)

  STAGE(0, 0);
  // s=0
  STAGE(1, 1);
  BAR_ACQ(8);          // slab 0 resident; slab 1's 8 loads still in flight
  COMPUTE(0);
  BAR_REL();           // all waves done with buf0 -> s=1 may overwrite it
  // s=1
  STAGE(0, 2);
  BAR_ACQ(8);          // slab 1 resident; slab 2 in flight
  COMPUTE(1);
  BAR_REL();
  // s=2
  STAGE(1, 3);
  BAR_ACQ(8);          // slab 2 resident; slab 3 in flight
  COMPUTE(0);
  // no overwrite follows; next BAR_ACQ suffices
  // s=3
  BAR_ACQ(0);          // slab 3 resident
  COMPUTE(1);

#undef STAGE
#undef COMPUTE
#undef BAR_ACQ
#undef BAR_REL

  const int quad = lane >> 4, lc = lane & 15;

  // Diagonal: local row rg*128+fr*16+quad*4+r == local col cg*64+fc*16+lc
  // requires cg == 2*rg + (fr>>2), fc == fr&3, lc == quad*4+r.
  if (bR == bC) {
    #pragma unroll
    for (int fr = 0; fr < 8; ++fr) {
      if (cg == 2 * rg + (fr >> 2)) {
        #pragma unroll
        for (int r = 0; r < 4; ++r)
          if (lc == quad * 4 + r)
            diag[bR * 256 + rg * 128 + fr * 16 + lc] = acc[fr][fr & 3][r];
      }
    }
  }

  // Per-row partials over this wave's 64 cols (col-group bC*4+cg of 64).
  #pragma unroll
  for (int fr = 0; fr < 8; ++fr) {
    #pragma unroll
    for (int r = 0; r < 4; ++r) {
      float v0 = acc[fr][0][r], v1 = acc[fr][1][r];
      float v2 = acc[fr][2][r], v3 = acc[fr][3][r];
      float m = fmaxf(fmaxf(v0, v1), fmaxf(v2, v3));
      #pragma unroll
      for (int sh = 1; sh < 16; sh <<= 1) m = fmaxf(m, __shfl_xor(m, sh, 64));
      float ss = __expf(v0 - m) + __expf(v1 - m) +
                 __expf(v2 - m) + __expf(v3 - m);
      #pragma unroll
      for (int sh = 1; sh < 16; sh <<= 1) ss += __shfl_xor(ss, sh, 64);
      if (lc == 0) {
        int grow = bR * 256 + rg * 128 + fr * 16 + quad * 4 + r;
        int p = grow * 64 + bC * 4 + cg;
        pmax[p] = m; psum[p] = ss;
      }
    }
  }
}

// ---------------------------------------------------------------------------
// K2: per-row combine of 64 col-group partials -> loss/correct, block-reduce;
// last of 16 blocks finalizes (16 fences total -- round-1 lesson: fences
// scale catastrophically, keep the count tiny).
// ---------------------------------------------------------------------------
__global__ __launch_bounds__(256) void combine_rows(
    const float* __restrict__ pmax, const float* __restrict__ psum,
    const float* __restrict__ diag,
    float* __restrict__ lpart, float* __restrict__ cpart,
    int* __restrict__ cnt, float* __restrict__ out) {
  int row = blockIdx.x * 256 + threadIdx.x;
  const float* pm = pmax + row * 64;
  const float* ps = psum + row * 64;
  float M = -3.4e38f;
  #pragma unroll 8
  for (int b = 0; b < 64; ++b) M = fmaxf(M, pm[b]);
  float S = 0.f;
  #pragma unroll 8
  for (int b = 0; b < 64; ++b) S += ps[b] * __expf(pm[b] - M);
  float d = diag[row];
  float lossr = logf(S) + M - d;
  float corr = (d == M) ? 1.f : 0.f;
  #pragma unroll
  for (int sh = 1; sh < 64; sh <<= 1) {
    lossr += __shfl_xor(lossr, sh, 64);
    corr  += __shfl_xor(corr,  sh, 64);
  }
  __shared__ float ls[4], cs[4];
  int wave = threadIdx.x >> 6, lane = threadIdx.x & 63;
  if (lane == 0) { ls[wave] = lossr; cs[wave] = corr; }
  __syncthreads();
  if (threadIdx.x == 0) {
    lpart[blockIdx.x] = ls[0] + ls[1] + ls[2] + ls[3];
    cpart[blockIdx.x] = cs[0] + cs[1] + cs[2] + cs[3];
    __threadfence();                     // release per-block partial
    if (atomicAdd(cnt, 1) == 15) {       // last arriver finalizes
      __threadfence();                   // acquire all partials
      float L = 0.f, C = 0.f;
      for (int i = 0; i < 16; ++i) { L += lpart[i]; C += cpart[i]; }
      out[0] = L * (1.f / 4096.f);
      out[1] = C * (100.f / 4096.f);
    }
  }
}

extern "C" void kernel_launch(void* const* d_in, const int* in_sizes, int n_in,
                              void* d_out, int out_size, void* d_ws, size_t ws_size,
                              hipStream_t stream) {
  const float* pred = (const float*)d_in[0];
  const float* gt   = (const float*)d_in[1];
  char* w = (char*)d_ws;
  unsigned short* Xbf = (unsigned short*)(w + OFF_X);
  unsigned short* Ybf = (unsigned short*)(w + OFF_Y);
  float* pmax  = (float*)(w + OFF_PMAX);
  float* psum  = (float*)(w + OFF_PSUM);
  float* diag  = (float*)(w + OFF_DIAG);
  float* lpart = (float*)(w + OFF_LPART);
  float* cpart = (float*)(w + OFF_CPART);
  int*   cnt   = (int*)(w + OFF_CNT);
  float* out   = (float*)d_out;

  transpose_stage<<<512, 256, 0, stream>>>(pred, gt, Xbf, Ybf, cnt);
  gemm_softmax_partial<<<256, 512, 0, stream>>>(Xbf, Ybf, pmax, psum, diag);
  combine_rows<<<16, 256, 0, stream>>>(pmax, psum, diag, lpart, cpart, cnt, out);
}